// Round 8
// baseline (583.118 us; speedup 1.0000x reference)
//
#include <hip/hip_runtime.h>

// Problem constants (B,S,E,H,DK,DV,DF) = (4,2048,512,8,64,64,2048)
#define Bx  4
#define Sx  2048
#define Ex  512
#define Hx  8
#define Tt  (Bx * Sx)          // 8192 tokens

typedef short          short8 __attribute__((ext_vector_type(8)));  // 8 bf16
typedef float          f32x4  __attribute__((ext_vector_type(4)));  // MFMA C/D
typedef unsigned int   u32x4  __attribute__((ext_vector_type(4)));
typedef unsigned short u16;

__device__ __forceinline__ u16 f2bf(float f) {
    unsigned int u = __float_as_uint(f);
    u += 0x7fffu + ((u >> 16) & 1u);          // round-to-nearest-even
    return (u16)(u >> 16);
}
__device__ __forceinline__ float bf2f(u16 h) {
    return __uint_as_float(((unsigned int)h) << 16);
}

// ---------------------------------------------------------------------------
// fp32 -> bf16 flat convert. n divisible by 1024.
// ---------------------------------------------------------------------------
__global__ __launch_bounds__(256) void f32_to_bf16(const float* __restrict__ in,
                                                   u16* __restrict__ out)
{
    int i = (blockIdx.x * 256 + threadIdx.x) << 2;
    float4 v = *(const float4*)(in + i);
    ushort4 o;
    o.x = f2bf(v.x); o.y = f2bf(v.y); o.z = f2bf(v.z); o.w = f2bf(v.w);
    *(ushort4*)(out + i) = o;
}

// ---------------------------------------------------------------------------
// W (K x N fp32, row-major) -> Wt (N x K bf16, row-major). 32x32 LDS tiles.
// ---------------------------------------------------------------------------
__global__ __launch_bounds__(256) void transpose_bf16(const float* __restrict__ W,
                                                      u16* __restrict__ Wt,
                                                      int K, int N)
{
    __shared__ u16 tile[32][33];
    const int n0 = blockIdx.x * 32, k0 = blockIdx.y * 32;
    const int tx = threadIdx.x & 31, ty = threadIdx.x >> 5;   // ty 0..7
#pragma unroll
    for (int i = 0; i < 32; i += 8)
        tile[ty + i][tx] = f2bf(W[(size_t)(k0 + ty + i) * N + n0 + tx]);
    __syncthreads();
#pragma unroll
    for (int i = 0; i < 32; i += 8)
        Wt[(size_t)(n0 + ty + i) * K + k0 + tx] = tile[tx][ty + i];
}

// ---------------------------------------------------------------------------
// bf16 MFMA GEMM: C[M,N] = A[M,K] @ Bt[N,K]^T + bias[col], opt ReLU.
// Output row stride ldc (lets N=512 GEMMs write strided into fused buffers).
// 128x64 tile, BK=32, 128 thr = 2 waves; wave w = rows [w*64, w*64+64),
// 4x4 16x16x32 frags. LDS rows padded to 40 shorts. Register prefetch one
// K-step ahead. Grid: (N/64, M/128).
// ---------------------------------------------------------------------------
template<int OUT_BF16, int RELU>
__global__ __launch_bounds__(128) void gemm_mfma(const u16* __restrict__ A,
                                                 const u16* __restrict__ Bt,
                                                 const float* __restrict__ bias,
                                                 void* __restrict__ Cout,
                                                 int M, int N, int K, int ldc)
{
    __shared__ u16 As[128 * 40];
    __shared__ u16 Bs[64 * 40];

    const int tid  = threadIdx.x;
    const int w    = tid >> 6;
    const int lane = tid & 63;
    const int c    = lane & 15;
    const int quad = lane >> 4;
    const int m0   = blockIdx.y * 128;
    const int n0   = blockIdx.x * 64;

    const int rA = tid >> 2;            // 0..31
    const int kc = (tid & 3) << 3;      // 0,8,16,24

    const u16* Ap = A  + (size_t)(m0 + rA) * K + kc;
    const u16* Bp = Bt + (size_t)(n0 + rA) * K + kc;
    const size_t a32 = (size_t)32 * K;

    f32x4 acc[4][4];
#pragma unroll
    for (int i = 0; i < 4; i++)
#pragma unroll
        for (int j = 0; j < 4; j++) { acc[i][j][0]=0.f; acc[i][j][1]=0.f; acc[i][j][2]=0.f; acc[i][j][3]=0.f; }

    short8 ra[4], rb[2];
#pragma unroll
    for (int i = 0; i < 4; i++) ra[i] = *(const short8*)(Ap + i * a32);
#pragma unroll
    for (int i = 0; i < 2; i++) rb[i] = *(const short8*)(Bp + i * a32);

    for (int k0 = 0; k0 < K; k0 += 32) {
        __syncthreads();
#pragma unroll
        for (int i = 0; i < 4; i++) *(short8*)&As[(rA + i * 32) * 40 + kc] = ra[i];
#pragma unroll
        for (int i = 0; i < 2; i++) *(short8*)&Bs[(rA + i * 32) * 40 + kc] = rb[i];
        __syncthreads();

        if (k0 + 32 < K) {
#pragma unroll
            for (int i = 0; i < 4; i++) ra[i] = *(const short8*)(Ap + i * a32 + k0 + 32);
#pragma unroll
            for (int i = 0; i < 2; i++) rb[i] = *(const short8*)(Bp + i * a32 + k0 + 32);
        }

        short8 af[4], bf[4];
#pragma unroll
        for (int i = 0; i < 4; i++)
            af[i] = *(const short8*)&As[(w * 64 + i * 16 + c) * 40 + quad * 8];
#pragma unroll
        for (int j = 0; j < 4; j++)
            bf[j] = *(const short8*)&Bs[(j * 16 + c) * 40 + quad * 8];
#pragma unroll
        for (int i = 0; i < 4; i++)
#pragma unroll
            for (int j = 0; j < 4; j++)
                acc[i][j] = __builtin_amdgcn_mfma_f32_16x16x32_bf16(af[i], bf[j], acc[i][j], 0, 0, 0);
    }

    // ---- epilogue ----
    float bv[4];
#pragma unroll
    for (int j = 0; j < 4; j++) bv[j] = bias[n0 + j * 16 + c];

#pragma unroll
    for (int i = 0; i < 4; i++) {
#pragma unroll
        for (int j = 0; j < 4; j++) {
            int colg = n0 + j * 16 + c;
#pragma unroll
            for (int r = 0; r < 4; r++) {
                int rowg = m0 + w * 64 + i * 16 + quad * 4 + r;
                float v = acc[i][j][r] + bv[j];
                if (RELU) v = fmaxf(v, 0.f);
                if (OUT_BF16) ((u16*)Cout)[(size_t)rowg * ldc + colg] = f2bf(v);
                else          ((float*)Cout)[(size_t)rowg * ldc + colg] = v;
            }
        }
    }
}

// ---------------------------------------------------------------------------
// MFMA flash attention, 32 queries/wave, 128 q/block, 32-key tiles.
// Q/K/V row strides parametrized (fused QKV / KV buffers). O: (T,512) bf16.
//
// pi-interleaved key layout: u16 position p <-> key (p>>1) + ((p&1)<<4).
// P stored as packed u32 (keys c, c+16) at word row*20+c -> <=2-way bank
// aliasing. P read back as uint4 (same TBAA type as the stores) and
// bit-cast to short8 in-register; ordering via a block-uniform
// __syncthreads() (R7 bug: u32-store/short8-load punning ordered only by
// __threadfence_block() -- fences don't order non-atomic ops the TBAA says
// don't alias, so the load could hoist above the stores).
// V^T staged [dim][pi-pos] stride 40; pi applied to BOTH MFMA k-operands so
// the permutation cancels under contraction. No max-subtraction (|s|<~2):
// unnormalized O += P*V, l += sum(exp) == reference softmax; causal p=0 ==
// exp(-1e9) underflow. Layouts (m89/m91): A[m=lane&15][k=quad*8+j],
// B[k=quad*8+j][n=lane&15], C/D: col=lane&15, row=quad*4+reg.
// ---------------------------------------------------------------------------
template<bool CAUSAL>
__global__ __launch_bounds__(256) void attn_mfma(const u16* __restrict__ Q,
                                                 const u16* __restrict__ K,
                                                 const u16* __restrict__ V,
                                                 u16* __restrict__ O,
                                                 int ldq, int ldk, int ldv)
{
    __shared__ u16          Klds[32 * 72];       // [key][dim]
    __shared__ u16          Vtlds[64 * 40];      // [dim][pi-pos]
    __shared__ unsigned int Plds[4][32 * 20];    // per-wave [q][pi-word]

    const int tid  = threadIdx.x;
    const int w    = tid >> 6;
    const int lane = tid & 63;
    const int c    = lane & 15;
    const int quad = lane >> 4;
    const int q0   = blockIdx.x * 128;
    const int bh   = blockIdx.y;
    const int b    = bh >> 3;
    const int h    = bh & 7;
    const int bS   = b * Sx;
    const int hoff = h * 64;
    const int qw   = q0 + w * 32;                // wave's first query

    // K staging: thread owns (key = tid>>3, dim chunk (tid&7)*8)
    const int kkey = tid >> 3;
    const int kc8  = (tid & 7) << 3;
    // V staging: thread owns (dim = tid&63, pi-pos block (tid>>6)*8)
    const int vdim = tid & 63;
    const int vp   = (tid >> 6) << 3;
    const int kb2  = vp >> 1;                    // key base for pi-decode

    // Q fragments: rf row-frags, queries qw + rf*16 + c
    short8 qa[2][2];
#pragma unroll
    for (int rf = 0; rf < 2; rf++) {
        const u16* qp = Q + (size_t)(bS + qw + rf * 16 + c) * ldq + hoff;
        qa[rf][0] = *(const short8*)(qp + quad * 8);
        qa[rf][1] = *(const short8*)(qp + 32 + quad * 8);
    }

    f32x4 of[2][4];
#pragma unroll
    for (int rf = 0; rf < 2; rf++)
#pragma unroll
        for (int f = 0; f < 4; f++) { of[rf][f][0]=0.f; of[rf][f][1]=0.f; of[rf][f][2]=0.f; of[rf][f][3]=0.f; }
    float lpart[2][4] = {{0.f,0.f,0.f,0.f},{0.f,0.f,0.f,0.f}};

    const int kend = CAUSAL ? (q0 + 128) : Sx;
    for (int kt = 0; kt < kend; kt += 32) {
        __syncthreads();                         // (1) staging WAR protect
        // ---- stage K rows ----
        *(short8*)&Klds[kkey * 72 + kc8] =
            *(const short8*)(K + (size_t)(bS + kt + kkey) * ldk + hoff + kc8);
        // ---- stage V^T in pi order: 8 coalesced scalars -> one b128 ----
        {
            const u16* gv = V + (size_t)(bS + kt) * ldv + hoff + vdim;
            union { short8 v; u16 u[8]; } vb;
#pragma unroll
            for (int j = 0; j < 8; j++) {
                int key = kb2 + (j >> 1) + ((j & 1) << 4);
                vb.u[j] = gv[(size_t)key * ldv];
            }
            *(short8*)&Vtlds[vdim * 40 + vp] = vb.v;
        }
        __syncthreads();                         // (2) staging ready

        const bool live1 = !CAUSAL || (kt <= qw + 31);
        const bool live0 = !CAUSAL || (kt <= qw + 15);

        if (live1) {
            // K frags (shared across row-frags)
            short8 kb[2][2];
#pragma unroll
            for (int kf = 0; kf < 2; kf++) {
                kb[kf][0] = *(const short8*)&Klds[(kf * 16 + c) * 72 + quad * 8];
                kb[kf][1] = *(const short8*)&Klds[(kf * 16 + c) * 72 + 32 + quad * 8];
            }

            // S, P per live row-frag
#pragma unroll
            for (int rf = 0; rf < 2; rf++) {
                if (rf == 0 && !live0) continue;
                f32x4 s[2];
#pragma unroll
                for (int kf = 0; kf < 2; kf++) {
                    f32x4 z; z[0]=0.f; z[1]=0.f; z[2]=0.f; z[3]=0.f;
                    z = __builtin_amdgcn_mfma_f32_16x16x32_bf16(qa[rf][0], kb[kf][0], z, 0, 0, 0);
                    z = __builtin_amdgcn_mfma_f32_16x16x32_bf16(qa[rf][1], kb[kf][1], z, 0, 0, 0);
                    s[kf] = z;
                }
#pragma unroll
                for (int r = 0; r < 4; r++) {
                    int qg = qw + rf * 16 + quad * 4 + r;
                    float p0, p1;
                    if (CAUSAL && (kt + c) > qg) p0 = 0.f;
                    else p0 = __expf(s[0][r] * 0.125f);
                    if (CAUSAL && (kt + 16 + c) > qg) p1 = 0.f;
                    else p1 = __expf(s[1][r] * 0.125f);
                    u16 b0 = f2bf(p0), b1 = f2bf(p1);
                    lpart[rf][r] += bf2f(b0) + bf2f(b1);
                    Plds[w][(rf * 16 + quad * 4 + r) * 20 + c] =
                        (unsigned int)b0 | ((unsigned int)b1 << 16);
                }
            }
        }
        __syncthreads();                         // (3) P ready (block-uniform)

        if (live1) {
            // V frags (shared), then PV per live row-frag
            short8 vb[4];
#pragma unroll
            for (int f = 0; f < 4; f++)
                vb[f] = *(const short8*)&Vtlds[(f * 16 + c) * 40 + quad * 8];
#pragma unroll
            for (int rf = 0; rf < 2; rf++) {
                if (rf == 0 && !live0) continue;
                union { u32x4 u; short8 s; } pu;
                pu.u = *(const u32x4*)&Plds[w][(rf * 16 + c) * 20 + quad * 4];
                short8 pa = pu.s;
#pragma unroll
                for (int f = 0; f < 4; f++)
                    of[rf][f] = __builtin_amdgcn_mfma_f32_16x16x32_bf16(pa, vb[f], of[rf][f], 0, 0, 0);
            }
        }
    }

    // ---- denominators: sum over the quad's 16 lanes ----
#pragma unroll
    for (int rf = 0; rf < 2; rf++)
#pragma unroll
        for (int r = 0; r < 4; r++) {
            float v = lpart[rf][r];
            v += __shfl_xor(v, 1, 64);
            v += __shfl_xor(v, 2, 64);
            v += __shfl_xor(v, 4, 64);
            v += __shfl_xor(v, 8, 64);
            lpart[rf][r] = 1.f / v;
        }

    // ---- write O (bf16, stride 512): row = quad*4+r, col = f*16+c ----
#pragma unroll
    for (int rf = 0; rf < 2; rf++) {
        u16* Ob = O + (size_t)(bS + qw + rf * 16) * Ex + hoff;
#pragma unroll
        for (int f = 0; f < 4; f++)
#pragma unroll
            for (int r = 0; r < 4; r++)
                Ob[(size_t)(quad * 4 + r) * Ex + f * 16 + c] = f2bf(of[rf][f][r] * lpart[rf][r]);
    }
}

// ---------------------------------------------------------------------------
// Fused residual-add + LayerNorm over E=512; fp32 out + optional bf16 copy.
// ---------------------------------------------------------------------------
__global__ __launch_bounds__(256) void ln_add(const float* __restrict__ x,
                                              const float* __restrict__ s,
                                              const float* __restrict__ g,
                                              const float* __restrict__ bta,
                                              float* __restrict__ out,
                                              u16* __restrict__ out_bf)
{
    __shared__ float red[8];
    const int    row  = blockIdx.x;
    const int    t    = threadIdx.x;
    const size_t base = (size_t)row * Ex;

    float2 xv = *(const float2*)(x + base + (t << 1));
    float2 sv = *(const float2*)(s + base + (t << 1));
    float  y0 = xv.x + sv.x;
    float  y1 = xv.y + sv.y;

    float sum = y0 + y1;
    float sq  = y0 * y0 + y1 * y1;
#pragma unroll
    for (int o = 32; o > 0; o >>= 1) {
        sum += __shfl_down(sum, o, 64);
        sq  += __shfl_down(sq,  o, 64);
    }
    const int wid = t >> 6, lane = t & 63;
    if (lane == 0) { red[wid] = sum; red[4 + wid] = sq; }
    __syncthreads();
    if (t == 0) {
        red[0] = red[0] + red[1] + red[2] + red[3];
        red[4] = red[4] + red[5] + red[6] + red[7];
    }
    __syncthreads();

    const float mean = red[0] * (1.f / 512.f);
    const float var  = red[4] * (1.f / 512.f) - mean * mean;
    const float rstd = rsqrtf(var + 1e-3f);

    float2 gv = *(const float2*)(g   + (t << 1));
    float2 bv = *(const float2*)(bta + (t << 1));
    float  o0 = (y0 - mean) * rstd * gv.x + bv.x;
    float  o1 = (y1 - mean) * rstd * gv.y + bv.y;
    *(float2*)(out + base + (t << 1)) = make_float2(o0, o1);
    if (out_bf) {
        ushort2 ob; ob.x = f2bf(o0); ob.y = f2bf(o1);
        *(ushort2*)(out_bf + base + (t << 1)) = ob;
    }
}

// ---------------------------------------------------------------------------
// Orchestration. 96 MB workspace, byte offsets (MB):
//   [0,8)   bw: bf16 W^T x10 (exactly 8 MB)
//   [8,16)  xb     | P3: x2f = [8,24) fp32
//   [16,24) encb
//   [24,48) qkvB (stride 1536) | P2: qb=[24,32) str512, kvB=[32,48) str1024
//            | P3: ff1b = [24,56)
//   [48,56) ob (attn out, stride 512)
//   [56,72) projF fp32 (also ff2 out)
//   [72,88) x1f fp32
//   [88,96) x1b | P3: x2b
// ---------------------------------------------------------------------------
extern "C" void kernel_launch(void* const* d_in, const int* in_sizes, int n_in,
                              void* d_out, int out_size, void* d_ws, size_t ws_size,
                              hipStream_t stream)
{
    const float* x     = (const float*)d_in[0];
    const float* enc   = (const float*)d_in[1];
    const float* sa_Wq = (const float*)d_in[4],  *sa_bq = (const float*)d_in[5];
    const float* sa_Wk = (const float*)d_in[6],  *sa_bk = (const float*)d_in[7];
    const float* sa_Wv = (const float*)d_in[8],  *sa_bv = (const float*)d_in[9];
    const float* sa_Wo = (const float*)d_in[10], *sa_bo = (const float*)d_in[11];
    const float* ca_Wq = (const float*)d_in[12], *ca_bq = (const float*)d_in[13];
    const float* ca_Wk = (const float*)d_in[14], *ca_bk = (const float*)d_in[15];
    const float* ca_Wv = (const float*)d_in[16], *ca_bv = (const float*)d_in[17];
    const float* ca_Wo = (const float*)d_in[18], *ca_bo = (const float*)d_in[19];
    const float* ff_W1 = (const float*)d_in[20], *ff_b1 = (const float*)d_in[21];
    const float* ff_W2 = (const float*)d_in[22], *ff_b2 = (const float*)d_in[23];
    const float* ln1_g = (const float*)d_in[24], *ln1_b = (const float*)d_in[25];
    const float* ln2_g = (const float*)d_in[26], *ln2_b = (const float*)d_in[27];
    const float* ln3_g = (const float*)d_in[28], *ln3_b = (const float*)d_in[29];

    char* ws = (char*)d_ws;
    const size_t MB = 1024 * 1024;
    u16*   bw   = (u16*)(ws);
    u16*   xb   = (u16*)(ws + 8  * MB);
    u16*   encb = (u16*)(ws + 16 * MB);
    u16*   qkvB = (u16*)(ws + 24 * MB);
    u16*   qb   = (u16*)(ws + 24 * MB);
    u16*   kvB  = (u16*)(ws + 32 * MB);
    u16*   ff1b = (u16*)(ws + 24 * MB);
    u16*   ob   = (u16*)(ws + 48 * MB);
    float* projF= (float*)(ws + 56 * MB);
    float* x1f  = (float*)(ws + 72 * MB);
    u16*   x1b  = (u16*)(ws + 88 * MB);
    u16*   x2b  = (u16*)(ws + 88 * MB);
    float* x2f  = (float*)(ws + 8  * MB);

    // bf16 W^T slots (u16 element offsets); total = 4,194,304 u16 = 8 MB
    u16* wsaq = bw;                 u16* wsak = bw + 262144;
    u16* wsav = bw + 524288;        u16* wsao = bw + 786432;
    u16* wcaq = bw + 1048576;       u16* wcak = bw + 1310720;
    u16* wcav = bw + 1572864;       u16* wcao = bw + 1835008;
    u16* wff1 = bw + 2097152;       u16* wff2 = bw + 3145728;

    // ---- pre-pass ----
    f32_to_bf16<<<dim3(Tt * Ex / 1024), dim3(256), 0, stream>>>(x,   xb);
    f32_to_bf16<<<dim3(Tt * Ex / 1024), dim3(256), 0, stream>>>(enc, encb);
    auto TR = [&](const float* W, u16* Wt, int K, int N) {
        transpose_bf16<<<dim3(N / 32, K / 32), dim3(256), 0, stream>>>(W, Wt, K, N);
    };
    TR(sa_Wq, wsaq, 512, 512);  TR(sa_Wk, wsak, 512, 512);
    TR(sa_Wv, wsav, 512, 512);  TR(sa_Wo, wsao, 512, 512);
    TR(ca_Wq, wcaq, 512, 512);  TR(ca_Wk, wcak, 512, 512);
    TR(ca_Wv, wcav, 512, 512);  TR(ca_Wo, wcao, 512, 512);
    TR(ff_W1, wff1, 512, 2048); TR(ff_W2, wff2, 2048, 512);

    auto GEMM = [&](const u16* A, const u16* Wt, const float* bi, void* C,
                    int N, int K, int ldc, int out_bf, int relu) {
        dim3 grid(N / 64, Tt / 128);
        if (out_bf) {
            if (relu) gemm_mfma<1,1><<<grid, dim3(128), 0, stream>>>(A, Wt, bi, C, Tt, N, K, ldc);
            else      gemm_mfma<1,0><<<grid, dim3(128), 0, stream>>>(A, Wt, bi, C, Tt, N, K, ldc);
        } else        gemm_mfma<0,0><<<grid, dim3(128), 0, stream>>>(A, Wt, bi, C, Tt, N, K, ldc);
    };
    const dim3 agrid(Sx / 128, Bx * Hx);     // (16, 32)

    // ---- stage 1: QKV (strided into fused buffer) + self-attn + add&norm ----
    GEMM(xb, wsaq, sa_bq, qkvB,        512, 512, 1536, 1, 0);
    GEMM(xb, wsak, sa_bk, qkvB + 512,  512, 512, 1536, 1, 0);
    GEMM(xb, wsav, sa_bv, qkvB + 1024, 512, 512, 1536, 1, 0);
    attn_mfma<true><<<agrid, dim3(256), 0, stream>>>(qkvB, qkvB + 512, qkvB + 1024,
                                                     ob, 1536, 1536, 1536);
    GEMM(ob, wsao, sa_bo, projF, 512, 512, 512, 0, 0);
    ln_add<<<dim3(Tt), dim3(256), 0, stream>>>(x, projF, ln1_g, ln1_b, x1f, x1b);

    // ---- stage 2: cross-attention + add&norm ----
    GEMM(x1b,  wcaq, ca_bq, qb,        512, 512, 512,  1, 0);
    GEMM(encb, wcak, ca_bk, kvB,       512, 512, 1024, 1, 0);
    GEMM(encb, wcav, ca_bv, kvB + 512, 512, 512, 1024, 1, 0);
    attn_mfma<false><<<agrid, dim3(256), 0, stream>>>(qb, kvB, kvB + 512,
                                                      ob, 512, 1024, 1024);
    GEMM(ob, wcao, ca_bo, projF, 512, 512, 512, 0, 0);
    ln_add<<<dim3(Tt), dim3(256), 0, stream>>>(x1f, projF, ln2_g, ln2_b, x2f, x2b);

    // ---- stage 3: FFN + add&norm ----
    GEMM(x2b, wff1, ff_b1, ff1b, 2048, 512, 2048, 1, 1);     // ReLU
    GEMM(ff1b, wff2, ff_b2, projF, 512, 2048, 512, 0, 0);
    ln_add<<<dim3(Tt), dim3(256), 0, stream>>>(x2f, projF, ln3_g, ln3_b,
                                               (float*)d_out, (u16*)nullptr);
}

// Round 9
// 553.773 us; speedup vs baseline: 1.0530x; 1.0530x over previous
//
#include <hip/hip_runtime.h>

// Problem constants (B,S,E,H,DK,DV,DF) = (4,2048,512,8,64,64,2048)
#define Bx  4
#define Sx  2048
#define Ex  512
#define Hx  8
#define Tt  (Bx * Sx)          // 8192 tokens

typedef short          short8 __attribute__((ext_vector_type(8)));  // 8 bf16
typedef float          f32x4  __attribute__((ext_vector_type(4)));  // MFMA C/D
typedef unsigned int   u32x4  __attribute__((ext_vector_type(4)));
typedef unsigned short u16;

__device__ __forceinline__ u16 f2bf(float f) {
    unsigned int u = __float_as_uint(f);
    u += 0x7fffu + ((u >> 16) & 1u);          // round-to-nearest-even
    return (u16)(u >> 16);
}
__device__ __forceinline__ float bf2f(u16 h) {
    return __uint_as_float(((unsigned int)h) << 16);
}

// ---------------------------------------------------------------------------
// fp32 -> bf16 flat convert, two tensors in one dispatch (grid.y selects).
// ---------------------------------------------------------------------------
__global__ __launch_bounds__(256) void f32_to_bf16_2(const float* __restrict__ a,
                                                     const float* __restrict__ b,
                                                     u16* __restrict__ oa,
                                                     u16* __restrict__ ob)
{
    const float* in  = blockIdx.y ? b : a;
    u16*         out = blockIdx.y ? ob : oa;
    int i = (blockIdx.x * 256 + threadIdx.x) << 2;
    float4 v = *(const float4*)(in + i);
    ushort4 o;
    o.x = f2bf(v.x); o.y = f2bf(v.y); o.z = f2bf(v.z); o.w = f2bf(v.w);
    *(ushort4*)(out + i) = o;
}

// ---------------------------------------------------------------------------
// W (K x N fp32) -> Wt (N x K bf16). Generic (for ff_W1/ff_W2).
// ---------------------------------------------------------------------------
__global__ __launch_bounds__(256) void transpose_bf16(const float* __restrict__ W,
                                                      u16* __restrict__ Wt,
                                                      int K, int N)
{
    __shared__ u16 tile[32][33];
    const int n0 = blockIdx.x * 32, k0 = blockIdx.y * 32;
    const int tx = threadIdx.x & 31, ty = threadIdx.x >> 5;   // ty 0..7
#pragma unroll
    for (int i = 0; i < 32; i += 8)
        tile[ty + i][tx] = f2bf(W[(size_t)(k0 + ty + i) * N + n0 + tx]);
    __syncthreads();
#pragma unroll
    for (int i = 0; i < 32; i += 8)
        Wt[(size_t)(n0 + ty + i) * K + k0 + tx] = tile[tx][ty + i];
}

// ---------------------------------------------------------------------------
// 8x 512x512 transposes in one dispatch; slot z writes base + z*262144.
// ---------------------------------------------------------------------------
struct WPtrs { const float* w[8]; };
__global__ __launch_bounds__(256) void transpose8_bf16(WPtrs ws, u16* __restrict__ base)
{
    __shared__ u16 tile[32][33];
    const float* W  = ws.w[blockIdx.z];
    u16*         Wt = base + (size_t)blockIdx.z * 262144;
    const int n0 = blockIdx.x * 32, k0 = blockIdx.y * 32;
    const int tx = threadIdx.x & 31, ty = threadIdx.x >> 5;
#pragma unroll
    for (int i = 0; i < 32; i += 8)
        tile[ty + i][tx] = f2bf(W[(size_t)(k0 + ty + i) * 512 + n0 + tx]);
    __syncthreads();
#pragma unroll
    for (int i = 0; i < 32; i += 8)
        Wt[(size_t)(n0 + ty + i) * 512 + k0 + tx] = tile[tx][ty + i];
}

// ---------------------------------------------------------------------------
// bf16 MFMA GEMM (R5 shape): C[M,N] = A[M,K] @ Bt[N,K]^T + bias, opt ReLU.
// 128x128 tile, BK=32, 256 thr = 4 waves (2x2), wave tile 64x64 (4x4 frags).
// LDS rows padded to 40 shorts. Register prefetch one K-step ahead.
// Output row stride ldc (fused strided buffers). Grid: (N/128, M/128).
// ---------------------------------------------------------------------------
template<int OUT_BF16, int RELU>
__global__ __launch_bounds__(256) void gemm_mfma(const u16* __restrict__ A,
                                                 const u16* __restrict__ Bt,
                                                 const float* __restrict__ bias,
                                                 void* __restrict__ Cout,
                                                 int M, int N, int K, int ldc)
{
    __shared__ u16 As[128 * 40];
    __shared__ u16 Bs[128 * 40];

    const int tid  = threadIdx.x;
    const int w    = tid >> 6;
    const int lane = tid & 63;
    const int c    = lane & 15;
    const int quad = lane >> 4;
    const int wr   = w >> 1, wc = w & 1;
    const int m0   = blockIdx.y * 128;
    const int n0   = blockIdx.x * 128;

    const int row0 = tid >> 2;           // 0..63
    const int kc   = (tid & 3) << 3;     // 0,8,16,24

    const u16* Ap = A  + (size_t)(m0 + row0) * K + kc;
    const u16* Bp = Bt + (size_t)(n0 + row0) * K + kc;
    const size_t rstep = (size_t)64 * K;

    f32x4 acc[4][4];
#pragma unroll
    for (int i = 0; i < 4; i++)
#pragma unroll
        for (int j = 0; j < 4; j++) { acc[i][j][0]=0.f; acc[i][j][1]=0.f; acc[i][j][2]=0.f; acc[i][j][3]=0.f; }

    short8 ra0 = *(const short8*)(Ap);
    short8 ra1 = *(const short8*)(Ap + rstep);
    short8 rb0 = *(const short8*)(Bp);
    short8 rb1 = *(const short8*)(Bp + rstep);

    for (int k0 = 0; k0 < K; k0 += 32) {
        __syncthreads();
        *(short8*)&As[row0 * 40 + kc]        = ra0;
        *(short8*)&As[(row0 + 64) * 40 + kc] = ra1;
        *(short8*)&Bs[row0 * 40 + kc]        = rb0;
        *(short8*)&Bs[(row0 + 64) * 40 + kc] = rb1;
        __syncthreads();

        if (k0 + 32 < K) {
            ra0 = *(const short8*)(Ap + k0 + 32);
            ra1 = *(const short8*)(Ap + rstep + k0 + 32);
            rb0 = *(const short8*)(Bp + k0 + 32);
            rb1 = *(const short8*)(Bp + rstep + k0 + 32);
        }

        short8 af[4], bf[4];
#pragma unroll
        for (int i = 0; i < 4; i++)
            af[i] = *(const short8*)&As[(wr * 64 + i * 16 + c) * 40 + quad * 8];
#pragma unroll
        for (int j = 0; j < 4; j++)
            bf[j] = *(const short8*)&Bs[(wc * 64 + j * 16 + c) * 40 + quad * 8];
#pragma unroll
        for (int i = 0; i < 4; i++)
#pragma unroll
            for (int j = 0; j < 4; j++)
                acc[i][j] = __builtin_amdgcn_mfma_f32_16x16x32_bf16(af[i], bf[j], acc[i][j], 0, 0, 0);
    }

    // ---- epilogue ----
    float bv[4];
#pragma unroll
    for (int j = 0; j < 4; j++) bv[j] = bias[n0 + wc * 64 + j * 16 + c];

#pragma unroll
    for (int i = 0; i < 4; i++) {
#pragma unroll
        for (int j = 0; j < 4; j++) {
            int colg = n0 + wc * 64 + j * 16 + c;
#pragma unroll
            for (int r = 0; r < 4; r++) {
                int rowg = m0 + wr * 64 + i * 16 + quad * 4 + r;
                float v = acc[i][j][r] + bv[j];
                if (RELU) v = fmaxf(v, 0.f);
                if (OUT_BF16) ((u16*)Cout)[(size_t)rowg * ldc + colg] = f2bf(v);
                else          ((float*)Cout)[(size_t)rowg * ldc + colg] = v;
            }
        }
    }
}

// ---------------------------------------------------------------------------
// MFMA flash attention: 64 q/block (4 waves x 16 q), 64-key tiles.
// Grid (S/64, B*H) = 1024 blocks -> ~5 blocks/CU (27.6 KB LDS).
// 3 block barriers per 64 keys. pi-interleaved P (u32 words: keys c,c+16 per
// 32-key group) and V^T staged in the same pi order, so the MFMA k-order
// permutation cancels. P readback as u32x4 (TBAA-matching), ordered by a
// block-uniform __syncthreads (R7 lesson). Causal: diagonal tile computes
// only fmax=w+1 key-frags; per-element mask inside. No max-subtraction
// (|s|<~2): unnormalized O += P*V, l += sum(exp) == reference softmax;
// p=0 == exp(-1e9) underflow. Layouts (m89/m91): A[m=lane&15][k=quad*8+j],
// B[k=quad*8+j][n=lane&15], C/D: col=lane&15, row=quad*4+reg.
// ---------------------------------------------------------------------------
template<bool CAUSAL>
__global__ __launch_bounds__(256) void attn_mfma(const u16* __restrict__ Q,
                                                 const u16* __restrict__ K,
                                                 const u16* __restrict__ V,
                                                 u16* __restrict__ O,
                                                 int ldq, int ldk, int ldv)
{
    __shared__ u16          Klds[64 * 72];       // [key][dim]
    __shared__ u16          Vtlds[64 * 72];      // [dim][pi-pos 0..63]
    __shared__ unsigned int Plds[4][16 * 36];    // per-wave [q][grp0 16w |2pad| grp1 16w |2pad]

    const int tid  = threadIdx.x;
    const int w    = tid >> 6;
    const int lane = tid & 63;
    const int c    = lane & 15;
    const int quad = lane >> 4;
    const int q0   = blockIdx.x * 64;
    const int bh   = blockIdx.y;
    const int b    = bh >> 3;
    const int h    = bh & 7;
    const int bS   = b * Sx;
    const int hoff = h * 64;
    const int qw   = q0 + w * 16;                // wave's first query

    // V^T staging: thread owns dim = tid&63 and pi-pos block vp = (tid>>6)*16
    const int vdim = tid & 63;
    const int vp   = (tid >> 6) << 4;

    // Q fragments: queries qw + c, dims in 2 k-frags
    short8 qa[2];
    {
        const u16* qp = Q + (size_t)(bS + qw + c) * ldq + hoff;
        qa[0] = *(const short8*)(qp + quad * 8);
        qa[1] = *(const short8*)(qp + 32 + quad * 8);
    }

    f32x4 of[4];
#pragma unroll
    for (int f = 0; f < 4; f++) { of[f][0]=0.f; of[f][1]=0.f; of[f][2]=0.f; of[f][3]=0.f; }
    float lpart[4] = {0.f, 0.f, 0.f, 0.f};

    const int kend = CAUSAL ? (q0 + 64) : Sx;
    for (int kt = 0; kt < kend; kt += 64) {
        __syncthreads();                         // (1) WAR: prior reads done
        // ---- stage K rows: 2 b128 per thread ----
#pragma unroll
        for (int i = 0; i < 2; i++) {
            int chunk = tid + (i << 8);          // 0..511
            int row   = chunk >> 3;              // 0..63
            int c8    = (chunk & 7) << 3;
            *(short8*)&Klds[row * 72 + c8] =
                *(const short8*)(K + (size_t)(bS + kt + row) * ldk + hoff + c8);
        }
        // ---- stage V^T in pi order: 16 coalesced scalars -> 2 b128 ----
        {
            const u16* gv = V + (size_t)(bS + kt) * ldv + hoff + vdim;
            union { short8 v; u16 u[8]; } v0, v1;
#pragma unroll
            for (int j = 0; j < 8; j++) {
                int pos = vp + j;
                int g = pos >> 5, pp = pos & 31;
                v0.u[j] = gv[(size_t)((g << 5) + (pp >> 1) + ((pp & 1) << 4)) * ldv];
            }
#pragma unroll
            for (int j = 0; j < 8; j++) {
                int pos = vp + 8 + j;
                int g = pos >> 5, pp = pos & 31;
                v1.u[j] = gv[(size_t)((g << 5) + (pp >> 1) + ((pp & 1) << 4)) * ldv];
            }
            *(short8*)&Vtlds[vdim * 72 + vp]     = v0.v;
            *(short8*)&Vtlds[vdim * 72 + vp + 8] = v1.v;
        }
        __syncthreads();                         // (2) staging ready

        int fmax = 4;
        if (CAUSAL) {
            int d = ((qw + 15 - kt) >> 4) + 1;   // >=1 always (kt <= q0 <= qw)
            fmax = d < 4 ? d : 4;
        }

        // ---- S = Q K^T for live key-frags ----
        f32x4 s[4];
#pragma unroll
        for (int f = 0; f < 4; f++) {
            if (f < fmax) {
                short8 kb0 = *(const short8*)&Klds[(f * 16 + c) * 72 + quad * 8];
                short8 kb1 = *(const short8*)&Klds[(f * 16 + c) * 72 + 32 + quad * 8];
                f32x4 z; z[0]=0.f; z[1]=0.f; z[2]=0.f; z[3]=0.f;
                z = __builtin_amdgcn_mfma_f32_16x16x32_bf16(qa[0], kb0, z, 0, 0, 0);
                z = __builtin_amdgcn_mfma_f32_16x16x32_bf16(qa[1], kb1, z, 0, 0, 0);
                s[f] = z;
            }
        }

        // ---- P = exp(S/8), packed u32 (keys c, c+16 of each 32-group) ----
#pragma unroll
        for (int fp = 0; fp < 2; fp++) {
            if (fp * 2 < fmax) {
                int f0 = fp * 2, f1 = fp * 2 + 1;
#pragma unroll
                for (int r = 0; r < 4; r++) {
                    int qg = qw + quad * 4 + r;
                    float p0 = 0.f, p1 = 0.f;
                    if (!(CAUSAL && (kt + f0 * 16 + c) > qg))
                        p0 = __expf(s[f0][r] * 0.125f);
                    if (f1 < fmax && !(CAUSAL && (kt + f1 * 16 + c) > qg))
                        p1 = __expf(s[f1][r] * 0.125f);
                    u16 b0 = f2bf(p0), b1 = f2bf(p1);
                    lpart[r] += bf2f(b0) + bf2f(b1);
                    Plds[w][(quad * 4 + r) * 36 + fp * 18 + c] =
                        (unsigned int)b0 | ((unsigned int)b1 << 16);
                }
            }
        }
        __syncthreads();                         // (3) P ready (block-uniform)

        // ---- O += P * V per live 32-key group ----
#pragma unroll
        for (int g = 0; g < 2; g++) {
            if (g * 2 < fmax) {
                union { u32x4 u; short8 s; } pu;
                pu.u = *(const u32x4*)&Plds[w][c * 36 + g * 18 + quad * 4];
                short8 pa = pu.s;
#pragma unroll
                for (int f2 = 0; f2 < 4; f2++) {
                    short8 vbf = *(const short8*)&Vtlds[(f2 * 16 + c) * 72 + (g << 5) + quad * 8];
                    of[f2] = __builtin_amdgcn_mfma_f32_16x16x32_bf16(pa, vbf, of[f2], 0, 0, 0);
                }
            }
        }
    }

    // ---- denominators: sum over the quad's 16 lanes ----
#pragma unroll
    for (int r = 0; r < 4; r++) {
        float v = lpart[r];
        v += __shfl_xor(v, 1, 64);
        v += __shfl_xor(v, 2, 64);
        v += __shfl_xor(v, 4, 64);
        v += __shfl_xor(v, 8, 64);
        lpart[r] = 1.f / v;
    }

    // ---- write O (bf16, stride 512): row = quad*4+r, col = f*16+c ----
    u16* Ob = O + (size_t)(bS + qw) * Ex + hoff;
#pragma unroll
    for (int f = 0; f < 4; f++)
#pragma unroll
        for (int r = 0; r < 4; r++)
            Ob[(size_t)(quad * 4 + r) * Ex + f * 16 + c] = f2bf(of[f][r] * lpart[r]);
}

// ---------------------------------------------------------------------------
// Fused residual-add + LayerNorm over E=512; fp32 out + optional bf16 copy.
// ---------------------------------------------------------------------------
__global__ __launch_bounds__(256) void ln_add(const float* __restrict__ x,
                                              const float* __restrict__ s,
                                              const float* __restrict__ g,
                                              const float* __restrict__ bta,
                                              float* __restrict__ out,
                                              u16* __restrict__ out_bf)
{
    __shared__ float red[8];
    const int    row  = blockIdx.x;
    const int    t    = threadIdx.x;
    const size_t base = (size_t)row * Ex;

    float2 xv = *(const float2*)(x + base + (t << 1));
    float2 sv = *(const float2*)(s + base + (t << 1));
    float  y0 = xv.x + sv.x;
    float  y1 = xv.y + sv.y;

    float sum = y0 + y1;
    float sq  = y0 * y0 + y1 * y1;
#pragma unroll
    for (int o = 32; o > 0; o >>= 1) {
        sum += __shfl_down(sum, o, 64);
        sq  += __shfl_down(sq,  o, 64);
    }
    const int wid = t >> 6, lane = t & 63;
    if (lane == 0) { red[wid] = sum; red[4 + wid] = sq; }
    __syncthreads();
    if (t == 0) {
        red[0] = red[0] + red[1] + red[2] + red[3];
        red[4] = red[4] + red[5] + red[6] + red[7];
    }
    __syncthreads();

    const float mean = red[0] * (1.f / 512.f);
    const float var  = red[4] * (1.f / 512.f) - mean * mean;
    const float rstd = rsqrtf(var + 1e-3f);

    float2 gv = *(const float2*)(g   + (t << 1));
    float2 bv = *(const float2*)(bta + (t << 1));
    float  o0 = (y0 - mean) * rstd * gv.x + bv.x;
    float  o1 = (y1 - mean) * rstd * gv.y + bv.y;
    *(float2*)(out + base + (t << 1)) = make_float2(o0, o1);
    if (out_bf) {
        ushort2 ob; ob.x = f2bf(o0); ob.y = f2bf(o1);
        *(ushort2*)(out_bf + base + (t << 1)) = ob;
    }
}

// ---------------------------------------------------------------------------
// Orchestration. 96 MB workspace, byte offsets (MB):
//   [0,8)   bw: bf16 W^T x10 (8 square slots contiguous, then ff1, ff2)
//   [8,16)  xb     | P3: x2f = [8,24) fp32
//   [16,24) encb
//   [24,48) qkvB (stride 1536) | P2: qb=[24,32) str512, kvB=[32,48) str1024
//            | P3: ff1b = [24,56)
//   [48,56) ob (attn out, stride 512)
//   [56,72) projF fp32 (also ff2 out)
//   [72,88) x1f fp32
//   [88,96) x1b | P3: x2b
// ---------------------------------------------------------------------------
extern "C" void kernel_launch(void* const* d_in, const int* in_sizes, int n_in,
                              void* d_out, int out_size, void* d_ws, size_t ws_size,
                              hipStream_t stream)
{
    const float* x     = (const float*)d_in[0];
    const float* enc   = (const float*)d_in[1];
    const float* sa_Wq = (const float*)d_in[4],  *sa_bq = (const float*)d_in[5];
    const float* sa_Wk = (const float*)d_in[6],  *sa_bk = (const float*)d_in[7];
    const float* sa_Wv = (const float*)d_in[8],  *sa_bv = (const float*)d_in[9];
    const float* sa_Wo = (const float*)d_in[10], *sa_bo = (const float*)d_in[11];
    const float* ca_Wq = (const float*)d_in[12], *ca_bq = (const float*)d_in[13];
    const float* ca_Wk = (const float*)d_in[14], *ca_bk = (const float*)d_in[15];
    const float* ca_Wv = (const float*)d_in[16], *ca_bv = (const float*)d_in[17];
    const float* ca_Wo = (const float*)d_in[18], *ca_bo = (const float*)d_in[19];
    const float* ff_W1 = (const float*)d_in[20], *ff_b1 = (const float*)d_in[21];
    const float* ff_W2 = (const float*)d_in[22], *ff_b2 = (const float*)d_in[23];
    const float* ln1_g = (const float*)d_in[24], *ln1_b = (const float*)d_in[25];
    const float* ln2_g = (const float*)d_in[26], *ln2_b = (const float*)d_in[27];
    const float* ln3_g = (const float*)d_in[28], *ln3_b = (const float*)d_in[29];

    char* ws = (char*)d_ws;
    const size_t MB = 1024 * 1024;
    u16*   bw   = (u16*)(ws);
    u16*   xb   = (u16*)(ws + 8  * MB);
    u16*   encb = (u16*)(ws + 16 * MB);
    u16*   qkvB = (u16*)(ws + 24 * MB);
    u16*   qb   = (u16*)(ws + 24 * MB);
    u16*   kvB  = (u16*)(ws + 32 * MB);
    u16*   ff1b = (u16*)(ws + 24 * MB);
    u16*   ob   = (u16*)(ws + 48 * MB);
    float* projF= (float*)(ws + 56 * MB);
    float* x1f  = (float*)(ws + 72 * MB);
    u16*   x1b  = (u16*)(ws + 88 * MB);
    u16*   x2b  = (u16*)(ws + 88 * MB);
    float* x2f  = (float*)(ws + 8  * MB);

    // bf16 W^T slots: 8 squares contiguous (transpose8 order), then ff1/ff2
    u16* wsaq = bw;                 u16* wsak = bw + 262144;
    u16* wsav = bw + 524288;        u16* wsao = bw + 786432;
    u16* wcaq = bw + 1048576;       u16* wcak = bw + 1310720;
    u16* wcav = bw + 1572864;       u16* wcao = bw + 1835008;
    u16* wff1 = bw + 2097152;       u16* wff2 = bw + 3145728;

    // ---- pre-pass (4 launches) ----
    f32_to_bf16_2<<<dim3(Tt * Ex / 1024, 2), dim3(256), 0, stream>>>(x, enc, xb, encb);
    WPtrs wp; wp.w[0]=sa_Wq; wp.w[1]=sa_Wk; wp.w[2]=sa_Wv; wp.w[3]=sa_Wo;
    wp.w[4]=ca_Wq; wp.w[5]=ca_Wk; wp.w[6]=ca_Wv; wp.w[7]=ca_Wo;
    transpose8_bf16<<<dim3(16, 16, 8), dim3(256), 0, stream>>>(wp, bw);
    transpose_bf16<<<dim3(64, 16), dim3(256), 0, stream>>>(ff_W1, wff1, 512, 2048);
    transpose_bf16<<<dim3(16, 64), dim3(256), 0, stream>>>(ff_W2, wff2, 2048, 512);

    auto GEMM = [&](const u16* A, const u16* Wt, const float* bi, void* C,
                    int N, int K, int ldc, int out_bf, int relu) {
        dim3 grid(N / 128, Tt / 128);
        if (out_bf) {
            if (relu) gemm_mfma<1,1><<<grid, dim3(256), 0, stream>>>(A, Wt, bi, C, Tt, N, K, ldc);
            else      gemm_mfma<1,0><<<grid, dim3(256), 0, stream>>>(A, Wt, bi, C, Tt, N, K, ldc);
        } else        gemm_mfma<0,0><<<grid, dim3(256), 0, stream>>>(A, Wt, bi, C, Tt, N, K, ldc);
    };
    const dim3 agrid(Sx / 64, Bx * Hx);     // (32, 32)

    // ---- stage 1: QKV (strided into fused buffer) + self-attn + add&norm ----
    GEMM(xb, wsaq, sa_bq, qkvB,        512, 512, 1536, 1, 0);
    GEMM(xb, wsak, sa_bk, qkvB + 512,  512, 512, 1536, 1, 0);
    GEMM(xb, wsav, sa_bv, qkvB + 1024, 512, 512, 1536, 1, 0);
    attn_mfma<true><<<agrid, dim3(256), 0, stream>>>(qkvB, qkvB + 512, qkvB + 1024,
                                                     ob, 1536, 1536, 1536);
    GEMM(ob, wsao, sa_bo, projF, 512, 512, 512, 0, 0);
    ln_add<<<dim3(Tt), dim3(256), 0, stream>>>(x, projF, ln1_g, ln1_b, x1f, x1b);

    // ---- stage 2: cross-attention + add&norm ----
    GEMM(x1b,  wcaq, ca_bq, qb,        512, 512, 512,  1, 0);
    GEMM(encb, wcak, ca_bk, kvB,       512, 512, 1024, 1, 0);
    GEMM(encb, wcav, ca_bv, kvB + 512, 512, 512, 1024, 1, 0);
    attn_mfma<false><<<agrid, dim3(256), 0, stream>>>(qb, kvB, kvB + 512,
                                                      ob, 512, 1024, 1024);
    GEMM(ob, wcao, ca_bo, projF, 512, 512, 512, 0, 0);
    ln_add<<<dim3(Tt), dim3(256), 0, stream>>>(x1f, projF, ln2_g, ln2_b, x2f, x2b);

    // ---- stage 3: FFN + add&norm ----
    GEMM(x2b, wff1, ff_b1, ff1b, 2048, 512, 2048, 1, 1);     // ReLU
    GEMM(ff1b, wff2, ff_b2, projF, 512, 2048, 512, 0, 0);
    ln_add<<<dim3(Tt), dim3(256), 0, stream>>>(x2f, projF, ln3_g, ln3_b,
                                               (float*)d_out, (u16*)nullptr);
}

// Round 10
// 533.065 us; speedup vs baseline: 1.0939x; 1.0388x over previous
//
#include <hip/hip_runtime.h>

// Problem constants (B,S,E,H,DK,DV,DF) = (4,2048,512,8,64,64,2048)
#define Bx  4
#define Sx  2048
#define Ex  512
#define Hx  8
#define Tt  (Bx * Sx)          // 8192 tokens

typedef short          short8 __attribute__((ext_vector_type(8)));  // 8 bf16
typedef float          f32x4  __attribute__((ext_vector_type(4)));  // MFMA C/D
typedef unsigned short u16;

__device__ __forceinline__ u16 f2bf(float f) {
    unsigned int u = __float_as_uint(f);
    u += 0x7fffu + ((u >> 16) & 1u);          // round-to-nearest-even
    return (u16)(u >> 16);
}
__device__ __forceinline__ float bf2f(u16 h) {
    return __uint_as_float(((unsigned int)h) << 16);
}

// ---------------------------------------------------------------------------
// fp32 -> bf16 flat convert, two tensors in one dispatch (grid.y selects).
// ---------------------------------------------------------------------------
__global__ __launch_bounds__(256) void f32_to_bf16_2(const float* __restrict__ a,
                                                     const float* __restrict__ b,
                                                     u16* __restrict__ oa,
                                                     u16* __restrict__ ob)
{
    const float* in  = blockIdx.y ? b : a;
    u16*         out = blockIdx.y ? ob : oa;
    int i = (blockIdx.x * 256 + threadIdx.x) << 2;
    float4 v = *(const float4*)(in + i);
    ushort4 o;
    o.x = f2bf(v.x); o.y = f2bf(v.y); o.z = f2bf(v.z); o.w = f2bf(v.w);
    *(ushort4*)(out + i) = o;
}

// ---------------------------------------------------------------------------
// W (K x N fp32) -> Wt (N x K bf16). Generic (for ff_W1/ff_W2).
// ---------------------------------------------------------------------------
__global__ __launch_bounds__(256) void transpose_bf16(const float* __restrict__ W,
                                                      u16* __restrict__ Wt,
                                                      int K, int N)
{
    __shared__ u16 tile[32][33];
    const int n0 = blockIdx.x * 32, k0 = blockIdx.y * 32;
    const int tx = threadIdx.x & 31, ty = threadIdx.x >> 5;   // ty 0..7
#pragma unroll
    for (int i = 0; i < 32; i += 8)
        tile[ty + i][tx] = f2bf(W[(size_t)(k0 + ty + i) * N + n0 + tx]);
    __syncthreads();
#pragma unroll
    for (int i = 0; i < 32; i += 8)
        Wt[(size_t)(n0 + ty + i) * K + k0 + tx] = tile[tx][ty + i];
}

// ---------------------------------------------------------------------------
// 8x 512x512 transposes in one dispatch; slot z writes base + z*262144.
// ---------------------------------------------------------------------------
struct WPtrs { const float* w[8]; };
__global__ __launch_bounds__(256) void transpose8_bf16(WPtrs ws, u16* __restrict__ base)
{
    __shared__ u16 tile[32][33];
    const float* W  = ws.w[blockIdx.z];
    u16*         Wt = base + (size_t)blockIdx.z * 262144;
    const int n0 = blockIdx.x * 32, k0 = blockIdx.y * 32;
    const int tx = threadIdx.x & 31, ty = threadIdx.x >> 5;
#pragma unroll
    for (int i = 0; i < 32; i += 8)
        tile[ty + i][tx] = f2bf(W[(size_t)(k0 + ty + i) * 512 + n0 + tx]);
    __syncthreads();
#pragma unroll
    for (int i = 0; i < 32; i += 8)
        Wt[(size_t)(n0 + ty + i) * 512 + k0 + tx] = tile[tx][ty + i];
}

// ---------------------------------------------------------------------------
// gemm128: 128x128 tile, BK=32, 256 thr = 4 waves (2x2), wave 64x64.
// Bias segmented: column segment n0>>9 selects b0..b3 (supports fused
// QKV / KV outputs and N=2048 ff1). Output row stride ldc.
// ---------------------------------------------------------------------------
template<int OUT_BF16, int RELU>
__global__ __launch_bounds__(256) void gemm128(const u16* __restrict__ A,
                                               const u16* __restrict__ Bt,
                                               const float* __restrict__ b0,
                                               const float* __restrict__ b1,
                                               const float* __restrict__ b2,
                                               const float* __restrict__ b3,
                                               void* __restrict__ Cout,
                                               int M, int N, int K, int ldc)
{
    __shared__ u16 As[128 * 40];
    __shared__ u16 Bs[128 * 40];

    const int tid  = threadIdx.x;
    const int w    = tid >> 6;
    const int lane = tid & 63;
    const int c    = lane & 15;
    const int quad = lane >> 4;
    const int wr   = w >> 1, wc = w & 1;
    const int m0   = blockIdx.y * 128;
    const int n0   = blockIdx.x * 128;

    const int row0 = tid >> 2;           // 0..63
    const int kc   = (tid & 3) << 3;     // 0,8,16,24

    const u16* Ap = A  + (size_t)(m0 + row0) * K + kc;
    const u16* Bp = Bt + (size_t)(n0 + row0) * K + kc;
    const size_t rstep = (size_t)64 * K;

    f32x4 acc[4][4];
#pragma unroll
    for (int i = 0; i < 4; i++)
#pragma unroll
        for (int j = 0; j < 4; j++) { acc[i][j][0]=0.f; acc[i][j][1]=0.f; acc[i][j][2]=0.f; acc[i][j][3]=0.f; }

    short8 ra0 = *(const short8*)(Ap);
    short8 ra1 = *(const short8*)(Ap + rstep);
    short8 rb0 = *(const short8*)(Bp);
    short8 rb1 = *(const short8*)(Bp + rstep);

    for (int k0 = 0; k0 < K; k0 += 32) {
        __syncthreads();
        *(short8*)&As[row0 * 40 + kc]        = ra0;
        *(short8*)&As[(row0 + 64) * 40 + kc] = ra1;
        *(short8*)&Bs[row0 * 40 + kc]        = rb0;
        *(short8*)&Bs[(row0 + 64) * 40 + kc] = rb1;
        __syncthreads();

        if (k0 + 32 < K) {
            ra0 = *(const short8*)(Ap + k0 + 32);
            ra1 = *(const short8*)(Ap + rstep + k0 + 32);
            rb0 = *(const short8*)(Bp + k0 + 32);
            rb1 = *(const short8*)(Bp + rstep + k0 + 32);
        }

        short8 af[4], bf[4];
#pragma unroll
        for (int i = 0; i < 4; i++)
            af[i] = *(const short8*)&As[(wr * 64 + i * 16 + c) * 40 + quad * 8];
#pragma unroll
        for (int j = 0; j < 4; j++)
            bf[j] = *(const short8*)&Bs[(wc * 64 + j * 16 + c) * 40 + quad * 8];
#pragma unroll
        for (int i = 0; i < 4; i++)
#pragma unroll
            for (int j = 0; j < 4; j++)
                acc[i][j] = __builtin_amdgcn_mfma_f32_16x16x32_bf16(af[i], bf[j], acc[i][j], 0, 0, 0);
    }

    // ---- epilogue ----
    const int seg = n0 >> 9;
    const float* bp = seg == 0 ? b0 : (seg == 1 ? b1 : (seg == 2 ? b2 : b3));
    const int nbase = n0 & 511;
    float bv[4];
#pragma unroll
    for (int j = 0; j < 4; j++) bv[j] = bp[nbase + wc * 64 + j * 16 + c];

#pragma unroll
    for (int i = 0; i < 4; i++) {
#pragma unroll
        for (int j = 0; j < 4; j++) {
            int colg = n0 + wc * 64 + j * 16 + c;
#pragma unroll
            for (int r = 0; r < 4; r++) {
                int rowg = m0 + wr * 64 + i * 16 + quad * 4 + r;
                float v = acc[i][j][r] + bv[j];
                if (RELU) v = fmaxf(v, 0.f);
                if (OUT_BF16) ((u16*)Cout)[(size_t)rowg * ldc + colg] = f2bf(v);
                else          ((float*)Cout)[(size_t)rowg * ldc + colg] = v;
            }
        }
    }
}

// ---------------------------------------------------------------------------
// gemm64: 128x64 tile, BK=32, 128 thr = 2 waves. For N=512 GEMMs: grid
// (8,64) = 512 blocks = 2/CU (vs 1/CU with 128-wide tiles).
// ---------------------------------------------------------------------------
template<int OUT_BF16, int RELU>
__global__ __launch_bounds__(128) void gemm64(const u16* __restrict__ A,
                                              const u16* __restrict__ Bt,
                                              const float* __restrict__ bias,
                                              void* __restrict__ Cout,
                                              int M, int N, int K, int ldc)
{
    __shared__ u16 As[128 * 40];
    __shared__ u16 Bs[64 * 40];

    const int tid  = threadIdx.x;
    const int w    = tid >> 6;
    const int lane = tid & 63;
    const int c    = lane & 15;
    const int quad = lane >> 4;
    const int m0   = blockIdx.y * 128;
    const int n0   = blockIdx.x * 64;

    const int rA = tid >> 2;            // 0..31
    const int kc = (tid & 3) << 3;      // 0,8,16,24

    const u16* Ap = A  + (size_t)(m0 + rA) * K + kc;
    const u16* Bp = Bt + (size_t)(n0 + rA) * K + kc;
    const size_t a32 = (size_t)32 * K;

    f32x4 acc[4][4];
#pragma unroll
    for (int i = 0; i < 4; i++)
#pragma unroll
        for (int j = 0; j < 4; j++) { acc[i][j][0]=0.f; acc[i][j][1]=0.f; acc[i][j][2]=0.f; acc[i][j][3]=0.f; }

    short8 ra[4], rb[2];
#pragma unroll
    for (int i = 0; i < 4; i++) ra[i] = *(const short8*)(Ap + i * a32);
#pragma unroll
    for (int i = 0; i < 2; i++) rb[i] = *(const short8*)(Bp + i * a32);

    for (int k0 = 0; k0 < K; k0 += 32) {
        __syncthreads();
#pragma unroll
        for (int i = 0; i < 4; i++) *(short8*)&As[(rA + i * 32) * 40 + kc] = ra[i];
#pragma unroll
        for (int i = 0; i < 2; i++) *(short8*)&Bs[(rA + i * 32) * 40 + kc] = rb[i];
        __syncthreads();

        if (k0 + 32 < K) {
#pragma unroll
            for (int i = 0; i < 4; i++) ra[i] = *(const short8*)(Ap + i * a32 + k0 + 32);
#pragma unroll
            for (int i = 0; i < 2; i++) rb[i] = *(const short8*)(Bp + i * a32 + k0 + 32);
        }

        short8 af[4], bf[4];
#pragma unroll
        for (int i = 0; i < 4; i++)
            af[i] = *(const short8*)&As[(w * 64 + i * 16 + c) * 40 + quad * 8];
#pragma unroll
        for (int j = 0; j < 4; j++)
            bf[j] = *(const short8*)&Bs[(j * 16 + c) * 40 + quad * 8];
#pragma unroll
        for (int i = 0; i < 4; i++)
#pragma unroll
            for (int j = 0; j < 4; j++)
                acc[i][j] = __builtin_amdgcn_mfma_f32_16x16x32_bf16(af[i], bf[j], acc[i][j], 0, 0, 0);
    }

    float bv[4];
#pragma unroll
    for (int j = 0; j < 4; j++) bv[j] = bias[n0 + j * 16 + c];

#pragma unroll
    for (int i = 0; i < 4; i++) {
#pragma unroll
        for (int j = 0; j < 4; j++) {
            int colg = n0 + j * 16 + c;
#pragma unroll
            for (int r = 0; r < 4; r++) {
                int rowg = m0 + w * 64 + i * 16 + quad * 4 + r;
                float v = acc[i][j][r] + bv[j];
                if (RELU) v = fmaxf(v, 0.f);
                if (OUT_BF16) ((u16*)Cout)[(size_t)rowg * ldc + colg] = f2bf(v);
                else          ((float*)Cout)[(size_t)rowg * ldc + colg] = v;
            }
        }
    }
}

// ---------------------------------------------------------------------------
// MFMA flash attention (R5 structure + safe wave-local P):
// 64 q/block (4 waves x 16 q), 32-key tiles, TWO block barriers per tile
// (staging only). P round-trip is wave-local with NO barrier:
//   - pi-packed u32 words (keys c, c+16) at row stride 18 -> 2-way write
//     aliasing (free); stored AND loaded through volatile unsigned int*,
//     so the compiler cannot reorder them (R7 lesson: TBAA lets non-matching
//     non-volatile access cross a fence), and the LDS pipe is in-order
//     within a wave.
//   - V^T staged [dim][pi-pos] stride 40; pi applied to both MFMA k-operands
//     so the permutation cancels under contraction.
// Causal: fmax key-frag skip on diagonal tiles (no barrier inside).
// No max-subtraction (|s|<~2): unnormalized O += P*V, l += sum(exp) ==
// reference softmax; p=0 == exp(-1e9) underflow.
// Layouts (m89/m91): A[m=lane&15][k=quad*8+j], B[k=quad*8+j][n=lane&15],
// C/D: col=lane&15, row=quad*4+reg.
// ---------------------------------------------------------------------------
template<bool CAUSAL>
__global__ __launch_bounds__(256) void attn_mfma(const u16* __restrict__ Q,
                                                 const u16* __restrict__ K,
                                                 const u16* __restrict__ V,
                                                 u16* __restrict__ O,
                                                 int ldq, int ldk, int ldv)
{
    __shared__ u16          Klds[32 * 72];       // [key][dim]
    __shared__ u16          Vtlds[64 * 40];      // [dim][pi-pos], pad 8
    __shared__ unsigned int Plds[4][16 * 18];    // per-wave [q][pi-word], pad 2

    const int tid  = threadIdx.x;
    const int w    = tid >> 6;
    const int lane = tid & 63;
    const int c    = lane & 15;
    const int quad = lane >> 4;
    const int q0   = blockIdx.x * 64;
    const int bh   = blockIdx.y;
    const int b    = bh >> 3;
    const int h    = bh & 7;
    const int bS   = b * Sx;
    const int hoff = h * 64;
    const int qw   = q0 + w * 16;                // wave's first query

    // K staging: thread owns (key = tid>>3, dim chunk (tid&7)*8)
    const int kkey = tid >> 3;
    const int kc8  = (tid & 7) << 3;
    // V staging: thread owns (dim = tid&63, pi-pos block (tid>>6)*8)
    const int vdim = tid & 63;
    const int vp   = (tid >> 6) << 3;

    short8 qa[2];
    {
        const u16* qp = Q + (size_t)(bS + qw + c) * ldq + hoff;
        qa[0] = *(const short8*)(qp + quad * 8);
        qa[1] = *(const short8*)(qp + 32 + quad * 8);
    }

    f32x4 of[4];
#pragma unroll
    for (int f = 0; f < 4; f++) { of[f][0]=0.f; of[f][1]=0.f; of[f][2]=0.f; of[f][3]=0.f; }
    float lpart[4] = {0.f, 0.f, 0.f, 0.f};

    const int kend = CAUSAL ? (q0 + 64) : Sx;
    for (int kt = 0; kt < kend; kt += 32) {
        __syncthreads();                         // (1) WAR: prior reads done
        // ---- stage K rows: one b128 per thread ----
        *(short8*)&Klds[kkey * 72 + kc8] =
            *(const short8*)(K + (size_t)(bS + kt + kkey) * ldk + hoff + kc8);
        // ---- stage V^T in pi order: 8 coalesced scalars -> one b128 ----
        {
            const u16* gv = V + (size_t)(bS + kt) * ldv + hoff + vdim;
            union { short8 v; u16 u[8]; } vb;
#pragma unroll
            for (int j = 0; j < 8; j++) {
                int pos = vp + j;
                int key = (pos >> 1) + ((pos & 1) << 4);
                vb.u[j] = gv[(size_t)key * ldv];
            }
            *(short8*)&Vtlds[vdim * 40 + vp] = vb.v;
        }
        __syncthreads();                         // (2) staging ready

        int fmax = 2;
        if (CAUSAL) {
            int d = ((qw + 15 - kt) >> 4) + 1;   // arithmetic shift: can be <=0
            fmax = d < 2 ? d : 2;
        }

        if (fmax > 0) {
            // ---- S = Q K^T for live key-frags ----
            f32x4 s[2];
#pragma unroll
            for (int f = 0; f < 2; f++) {
                if (f < fmax) {
                    short8 kb0 = *(const short8*)&Klds[(f * 16 + c) * 72 + quad * 8];
                    short8 kb1 = *(const short8*)&Klds[(f * 16 + c) * 72 + 32 + quad * 8];
                    f32x4 z; z[0]=0.f; z[1]=0.f; z[2]=0.f; z[3]=0.f;
                    z = __builtin_amdgcn_mfma_f32_16x16x32_bf16(qa[0], kb0, z, 0, 0, 0);
                    z = __builtin_amdgcn_mfma_f32_16x16x32_bf16(qa[1], kb1, z, 0, 0, 0);
                    s[f] = z;
                }
            }

            // ---- P = exp(S/8), pi-packed u32, volatile store (wave-local) ----
#pragma unroll
            for (int r = 0; r < 4; r++) {
                int qg = qw + quad * 4 + r;
                float p0 = 0.f, p1 = 0.f;
                if (!(CAUSAL && (kt + c) > qg))
                    p0 = __expf(s[0][r] * 0.125f);
                if (fmax > 1 && !(CAUSAL && (kt + 16 + c) > qg))
                    p1 = __expf(s[1][r] * 0.125f);
                u16 b0 = f2bf(p0), b1 = f2bf(p1);
                lpart[r] += bf2f(b0) + bf2f(b1);
                *(volatile unsigned int*)&Plds[w][(quad * 4 + r) * 18 + c] =
                    (unsigned int)b0 | ((unsigned int)b1 << 16);
            }

            // ---- P readback (volatile, ordered after the stores) ----
            union { unsigned int u[4]; short8 s8; } pu;
#pragma unroll
            for (int i = 0; i < 4; i++)
                pu.u[i] = *(volatile const unsigned int*)&Plds[w][c * 18 + quad * 4 + i];
            short8 pa = pu.s8;

            // ---- O += P * V ----
#pragma unroll
            for (int f2 = 0; f2 < 4; f2++) {
                short8 vbf = *(const short8*)&Vtlds[(f2 * 16 + c) * 40 + quad * 8];
                of[f2] = __builtin_amdgcn_mfma_f32_16x16x32_bf16(pa, vbf, of[f2], 0, 0, 0);
            }
        }
    }

    // ---- denominators: sum over the quad's 16 lanes ----
#pragma unroll
    for (int r = 0; r < 4; r++) {
        float v = lpart[r];
        v += __shfl_xor(v, 1, 64);
        v += __shfl_xor(v, 2, 64);
        v += __shfl_xor(v, 4, 64);
        v += __shfl_xor(v, 8, 64);
        lpart[r] = 1.f / v;
    }

    // ---- write O (bf16, stride 512): row = quad*4+r, col = f*16+c ----
    u16* Ob = O + (size_t)(bS + qw) * Ex + hoff;
#pragma unroll
    for (int f = 0; f < 4; f++)
#pragma unroll
        for (int r = 0; r < 4; r++)
            Ob[(size_t)(quad * 4 + r) * Ex + f * 16 + c] = f2bf(of[f][r] * lpart[r]);
}

// ---------------------------------------------------------------------------
// Fused residual-add + LayerNorm over E=512; fp32 out + optional bf16 copy.
// ---------------------------------------------------------------------------
__global__ __launch_bounds__(256) void ln_add(const float* __restrict__ x,
                                              const float* __restrict__ s,
                                              const float* __restrict__ g,
                                              const float* __restrict__ bta,
                                              float* __restrict__ out,
                                              u16* __restrict__ out_bf)
{
    __shared__ float red[8];
    const int    row  = blockIdx.x;
    const int    t    = threadIdx.x;
    const size_t base = (size_t)row * Ex;

    float2 xv = *(const float2*)(x + base + (t << 1));
    float2 sv = *(const float2*)(s + base + (t << 1));
    float  y0 = xv.x + sv.x;
    float  y1 = xv.y + sv.y;

    float sum = y0 + y1;
    float sq  = y0 * y0 + y1 * y1;
#pragma unroll
    for (int o = 32; o > 0; o >>= 1) {
        sum += __shfl_down(sum, o, 64);
        sq  += __shfl_down(sq,  o, 64);
    }
    const int wid = t >> 6, lane = t & 63;
    if (lane == 0) { red[wid] = sum; red[4 + wid] = sq; }
    __syncthreads();
    if (t == 0) {
        red[0] = red[0] + red[1] + red[2] + red[3];
        red[4] = red[4] + red[5] + red[6] + red[7];
    }
    __syncthreads();

    const float mean = red[0] * (1.f / 512.f);
    const float var  = red[4] * (1.f / 512.f) - mean * mean;
    const float rstd = rsqrtf(var + 1e-3f);

    float2 gv = *(const float2*)(g   + (t << 1));
    float2 bv = *(const float2*)(bta + (t << 1));
    float  o0 = (y0 - mean) * rstd * gv.x + bv.x;
    float  o1 = (y1 - mean) * rstd * gv.y + bv.y;
    *(float2*)(out + base + (t << 1)) = make_float2(o0, o1);
    if (out_bf) {
        ushort2 ob; ob.x = f2bf(o0); ob.y = f2bf(o1);
        *(ushort2*)(out_bf + base + (t << 1)) = ob;
    }
}

// ---------------------------------------------------------------------------
// Orchestration. 96 MB workspace, byte offsets (MB):
//   [0,8)   bw: bf16 W^T x10 (8 square slots contiguous, then ff1, ff2)
//   [8,16)  xb     | P3: x2f = [8,24) fp32
//   [16,24) encb
//   [24,48) qkvB (stride 1536) | P2: qb=[24,32) str512, kvB=[32,48) str1024
//            | P3: ff1b = [24,56)
//   [48,56) ob (attn out, stride 512)
//   [56,72) projF fp32 (also ff2 out)
//   [72,88) x1f fp32
//   [88,96) x1b | P3: x2b
// ---------------------------------------------------------------------------
extern "C" void kernel_launch(void* const* d_in, const int* in_sizes, int n_in,
                              void* d_out, int out_size, void* d_ws, size_t ws_size,
                              hipStream_t stream)
{
    const float* x     = (const float*)d_in[0];
    const float* enc   = (const float*)d_in[1];
    const float* sa_Wq = (const float*)d_in[4],  *sa_bq = (const float*)d_in[5];
    const float* sa_Wk = (const float*)d_in[6],  *sa_bk = (const float*)d_in[7];
    const float* sa_Wv = (const float*)d_in[8],  *sa_bv = (const float*)d_in[9];
    const float* sa_Wo = (const float*)d_in[10], *sa_bo = (const float*)d_in[11];
    const float* ca_Wq = (const float*)d_in[12], *ca_bq = (const float*)d_in[13];
    const float* ca_Wk = (const float*)d_in[14], *ca_bk = (const float*)d_in[15];
    const float* ca_Wv = (const float*)d_in[16], *ca_bv = (const float*)d_in[17];
    const float* ca_Wo = (const float*)d_in[18], *ca_bo = (const float*)d_in[19];
    const float* ff_W1 = (const float*)d_in[20], *ff_b1 = (const float*)d_in[21];
    const float* ff_W2 = (const float*)d_in[22], *ff_b2 = (const float*)d_in[23];
    const float* ln1_g = (const float*)d_in[24], *ln1_b = (const float*)d_in[25];
    const float* ln2_g = (const float*)d_in[26], *ln2_b = (const float*)d_in[27];
    const float* ln3_g = (const float*)d_in[28], *ln3_b = (const float*)d_in[29];

    char* ws = (char*)d_ws;
    const size_t MB = 1024 * 1024;
    u16*   bw   = (u16*)(ws);
    u16*   xb   = (u16*)(ws + 8  * MB);
    u16*   encb = (u16*)(ws + 16 * MB);
    u16*   qkvB = (u16*)(ws + 24 * MB);
    u16*   qb   = (u16*)(ws + 24 * MB);
    u16*   kvB  = (u16*)(ws + 32 * MB);
    u16*   ff1b = (u16*)(ws + 24 * MB);
    u16*   ob   = (u16*)(ws + 48 * MB);
    float* projF= (float*)(ws + 56 * MB);
    float* x1f  = (float*)(ws + 72 * MB);
    u16*   x1b  = (u16*)(ws + 88 * MB);
    u16*   x2b  = (u16*)(ws + 88 * MB);
    float* x2f  = (float*)(ws + 8  * MB);

    // bf16 W^T slots: 8 squares contiguous (transpose8 order), then ff1/ff2
    u16* wsaq = bw;                 // QKV fused Bt = rows 0..1535 (q,k,v)
    u16* wsao = bw + 786432;
    u16* wcaq = bw + 1048576;
    u16* wcak = bw + 1310720;       // caKV fused Bt = rows 0..1023 (k,v)
    u16* wcao = bw + 1835008;
    u16* wff1 = bw + 2097152;
    u16* wff2 = bw + 3145728;

    // ---- pre-pass (4 launches) ----
    f32_to_bf16_2<<<dim3(Tt * Ex / 1024, 2), dim3(256), 0, stream>>>(x, enc, xb, encb);
    WPtrs wp; wp.w[0]=sa_Wq; wp.w[1]=sa_Wk; wp.w[2]=sa_Wv; wp.w[3]=sa_Wo;
    wp.w[4]=ca_Wq; wp.w[5]=ca_Wk; wp.w[6]=ca_Wv; wp.w[7]=ca_Wo;
    transpose8_bf16<<<dim3(16, 16, 8), dim3(256), 0, stream>>>(wp, bw);
    transpose_bf16<<<dim3(64, 16), dim3(256), 0, stream>>>(ff_W1, wff1, 512, 2048);
    transpose_bf16<<<dim3(16, 64), dim3(256), 0, stream>>>(ff_W2, wff2, 2048, 512);

    auto G128 = [&](const u16* A, const u16* Wt, const float* b0, const float* b1,
                    const float* b2, const float* b3, void* C,
                    int N, int K, int ldc, int out_bf, int relu) {
        dim3 grid(N / 128, Tt / 128);
        if (out_bf) {
            if (relu) gemm128<1,1><<<grid, dim3(256), 0, stream>>>(A, Wt, b0,b1,b2,b3, C, Tt, N, K, ldc);
            else      gemm128<1,0><<<grid, dim3(256), 0, stream>>>(A, Wt, b0,b1,b2,b3, C, Tt, N, K, ldc);
        } else        gemm128<0,0><<<grid, dim3(256), 0, stream>>>(A, Wt, b0,b1,b2,b3, C, Tt, N, K, ldc);
    };
    auto G64 = [&](const u16* A, const u16* Wt, const float* bi, void* C,
                   int K, int ldc, int out_bf) {
        dim3 grid(512 / 64, Tt / 128);
        if (out_bf) gemm64<1,0><<<grid, dim3(128), 0, stream>>>(A, Wt, bi, C, Tt, 512, K, ldc);
        else        gemm64<0,0><<<grid, dim3(128), 0, stream>>>(A, Wt, bi, C, Tt, 512, K, ldc);
    };
    const dim3 agrid(Sx / 64, Bx * Hx);     // (32, 32)

    // ---- stage 1: fused QKV GEMM + self-attn + add&norm ----
    G128(xb, wsaq, sa_bq, sa_bk, sa_bv, sa_bv, qkvB, 1536, 512, 1536, 1, 0);
    attn_mfma<true><<<agrid, dim3(256), 0, stream>>>(qkvB, qkvB + 512, qkvB + 1024,
                                                     ob, 1536, 1536, 1536);
    G64(ob, wsao, sa_bo, projF, 512, 512, 0);
    ln_add<<<dim3(Tt), dim3(256), 0, stream>>>(x, projF, ln1_g, ln1_b, x1f, x1b);

    // ---- stage 2: cross-attention + add&norm ----
    G64(x1b, wcaq, ca_bq, qb, 512, 512, 1);
    G128(encb, wcak, ca_bk, ca_bv, ca_bv, ca_bv, kvB, 1024, 512, 1024, 1, 0);
    attn_mfma<false><<<agrid, dim3(256), 0, stream>>>(qb, kvB, kvB + 512,
                                                      ob, 512, 1024, 1024);
    G64(ob, wcao, ca_bo, projF, 512, 512, 0);
    ln_add<<<dim3(Tt), dim3(256), 0, stream>>>(x1f, projF, ln2_g, ln2_b, x2f, x2b);

    // ---- stage 3: FFN + add&norm ----
    G128(x2b, wff1, ff_b1, ff_b1 + 512, ff_b1 + 1024, ff_b1 + 1536,
         ff1b, 2048, 512, 2048, 1, 1);                       // ReLU
    G64(ff1b, wff2, ff_b2, projF, 2048, 512, 0);
    ln_add<<<dim3(Tt), dim3(256), 0, stream>>>(x2f, projF, ln3_g, ln3_b,
                                               (float*)d_out, (u16*)nullptr);
}